// Round 1
// baseline (345.780 us; speedup 1.0000x reference)
//
#include <hip/hip_runtime.h>
#include <hip/hip_bf16.h>

// Problem constants (B=2, S=2048, DIM=1536, 12 heads x hd=128)
// Inputs fp32; OUTPUT fp32. Workspace ~94.8 MB (see kernel_launch).
#define SEQ    2048
#define TOK    4096          // B*S
#define DMODEL 1536
#define QKVROW 4608          // 3*DMODEL
#define HD     128
#define SCALE  0.08838834764831845f  // 1/sqrt(128)

#define NSPLIT 4
#define KRANGE (SEQ / NSPLIT)
#define NPAIR  12
#define ROWS_P (NPAIR * SEQ)
#define OPART_ELEMS ((size_t)ROWS_P * HD)

typedef __attribute__((ext_vector_type(8))) short short8;
typedef __attribute__((ext_vector_type(4))) short short4v;
typedef __attribute__((ext_vector_type(4))) float f32x4;

__device__ __forceinline__ float b2f(short s) {
    union { unsigned u; float f; } x;
    x.u = ((unsigned)(unsigned short)s) << 16;
    return x.f;
}
__device__ __forceinline__ short f2b(float f) {
    union { float f; unsigned u; } x; x.f = f;
    unsigned u = x.u;
    unsigned r = (u + 0x7fffu + ((u >> 16) & 1u)) >> 16;  // RNE
    return (short)r;
}

// async 16B global->LDS (m97 pattern). LDS dest: wave-uniform base + lane*16.
__device__ __forceinline__ void gld_lds16(const short* g, short* l) {
    __builtin_amdgcn_global_load_lds(
        (__attribute__((address_space(1))) void*)(g),
        (__attribute__((address_space(3))) void*)(l), 16, 0, 0);
}

// ---------------------------------------------------------------------------
// Fused prepass: x fp32->bf16, Wqkv/Wout fp32 -> transposed bf16.
// ---------------------------------------------------------------------------
#define CVT_BLOCKS  6144   // TOK*DMODEL / 1024
#define TQKV_BLOCKS 1728   // (QKVROW/64)*(DMODEL/64)
#define TOUT_BLOCKS 576    // (DMODEL/64)*(DMODEL/64)

__device__ __forceinline__ void transpose_tile(
    const float* __restrict__ W, short* __restrict__ WT,
    int K, int N, int k0, int n0, int t, short (*tile)[65])
{
    {
        int j  = t & 63;
        int i0 = (t >> 6) * 16;
        for (int ii = 0; ii < 16; ++ii)
            tile[i0 + ii][j] = f2b(W[(size_t)(k0 + i0 + ii) * N + n0 + j]);
    }
    __syncthreads();
    {
        int i  = t & 63;
        int j0 = (t >> 6) * 16;
        for (int jj = 0; jj < 16; ++jj)
            WT[(size_t)(n0 + j0 + jj) * K + k0 + i] = tile[i][j0 + jj];
    }
}

__global__ __launch_bounds__(256) void prepass_k(
    const float* __restrict__ x, const float* __restrict__ Wqkv,
    const float* __restrict__ Wout, short* __restrict__ xb,
    short* __restrict__ WqkvT, short* __restrict__ WoutT)
{
    __shared__ short tile[64][65];
    const int bid = blockIdx.x;
    const int t   = threadIdx.x;
    if (bid < CVT_BLOCKS) {
        int i = bid * 1024 + t * 4;
        float4 v = *(const float4*)(x + i);
        short4v b = { f2b(v.x), f2b(v.y), f2b(v.z), f2b(v.w) };
        *(short4v*)(xb + i) = b;
    } else if (bid < CVT_BLOCKS + TQKV_BLOCKS) {
        int tb = bid - CVT_BLOCKS;
        transpose_tile(Wqkv, WqkvT, DMODEL, QKVROW,
                       (tb / (QKVROW / 64)) * 64, (tb % (QKVROW / 64)) * 64, t, tile);
    } else {
        int tb = bid - (CVT_BLOCKS + TQKV_BLOCKS);
        transpose_tile(Wout, WoutT, DMODEL, DMODEL,
                       (tb / (DMODEL / 64)) * 64, (tb % (DMODEL / 64)) * 64, t, tile);
    }
}

// ---------------------------------------------------------------------------
// GEMM: 256x256 tile, BK=64, 8-phase counted-vmcnt schedule (T3+T4+T5).
//   C[M,N] = A[M,K] @ BT[N,K]^T + bias[N].
// 512 threads = 8 waves (2M x 4N); per-wave output 128x64; acc[8][4] f32x4.
// LDS 128 KiB = [slot:2][mat:A/B][kh:2][row-subtile:16][lane:64][8 shorts],
// i.e. FRAGMENT-ORDER: every ds_read_b128 is base + lane*16 -> conflict-free;
// global_load_lds (wave-uniform LDS dest) gets the permutation on the GLOBAL
// address side (m173 pattern).
//
// Stage unit = one matrix's K-half (256 rows x 32 k = 16 KB = 2 gld_lds16).
// Retirement within a K-tile's 4 phases: B-k0 after ph1, A-k0 after ph2,
// B-k1 after ph3, A-k1 after ph4 (register reuse of B across phase pairs).
// Steady-state stage stream, 1 unit/phase, tiles T (slot0, ph1-4) and
// T+1 (slot1, ph5-8) computed per iteration:
//   ph1: A-k1(T+1)->s1   ph2: B-k0(T+2)->s0  ph3: A-k0(T+2)->s0
//   ph4: B-k1(T+2)->s0 + vmcnt(6)            ph5: A-k1(T+2)->s0
//   ph6: B-k0(T+3)->s1   ph7: A-k0(T+3)->s1  ph8: B-k1(T+3)->s1 + vmcnt(6)
// vmcnt(6) = 3 units in flight; at each boundary the next tile's 4 units
// are exactly the issues older than the newest 3.  Tail: kt clamped to
// NT-1 (redundant re-stage of retired units, benign).
// ---------------------------------------------------------------------------
__device__ __forceinline__ short* ldsP(short* base, int slot, int mat, int kh, int st) {
    return base + (((slot * 2 + mat) * 2 + kh) * 16 + st) * 512;
}

template <int SLOT, int KH, int G>
__device__ __forceinline__ void ld_a(short8 af[4], short* smem, int wm8, int lane) {
#pragma unroll
    for (int mi = 0; mi < 4; ++mi)
        af[mi] = *(const short8*)(ldsP(smem, SLOT, 0, KH, wm8 + G * 4 + mi) + lane * 8);
}
template <int SLOT, int KH>
__device__ __forceinline__ void ld_b(short8 bf[4], short* smem, int wn4, int lane) {
#pragma unroll
    for (int ni = 0; ni < 4; ++ni)
        bf[ni] = *(const short8*)(ldsP(smem, SLOT, 1, KH, wn4 + ni) + lane * 8);
}
template <int G>
__device__ __forceinline__ void mfma16(f32x4 (&acc)[8][4], const short8 af[4], const short8 bf[4]) {
#pragma unroll
    for (int mi = 0; mi < 4; ++mi)
#pragma unroll
        for (int ni = 0; ni < 4; ++ni)
            acc[G * 4 + mi][ni] = __builtin_amdgcn_mfma_f32_16x16x32_bf16(
                af[mi], bf[ni], acc[G * 4 + mi][ni], 0, 0, 0);
}

__device__ __forceinline__ void stage2(const short* g0, const short* g1, int ko,
                                       short* d0, short* d1) {
    gld_lds16(g0 + ko, d0);
    gld_lds16(g1 + ko, d1);
}

#define STG_A(S, KH, KT) stage2(gA0, gA1, (KT) * 64 + (KH) * 32, \
        ldsP(smem, (S), 0, (KH), wave), ldsP(smem, (S), 0, (KH), 8 + wave))
#define STG_B(S, KH, KT) stage2(gB0, gB1, (KT) * 64 + (KH) * 32, \
        ldsP(smem, (S), 1, (KH), wave), ldsP(smem, (S), 1, (KH), 8 + wave))

#define PH(S, KH, G, LOADB, STG_STMT, VMW)                          \
    do {                                                            \
        ld_a<S, KH, G>(af, smem, wm8, lane);                        \
        if (LOADB) ld_b<S, KH>(bf, smem, wn4, lane);                \
        STG_STMT;                                                   \
        asm volatile("" ::: "memory");                              \
        __builtin_amdgcn_s_barrier();                               \
        asm volatile("s_waitcnt lgkmcnt(0)" ::: "memory");          \
        __builtin_amdgcn_s_setprio(1);                              \
        mfma16<G>(acc, af, bf);                                     \
        __builtin_amdgcn_s_setprio(0);                              \
        if (VMW) asm volatile("s_waitcnt vmcnt(6)" ::: "memory");   \
        asm volatile("" ::: "memory");                              \
        __builtin_amdgcn_s_barrier();                               \
        asm volatile("" ::: "memory");                              \
    } while (0)

template <bool OUT_BF16>
__global__ __launch_bounds__(512, 2) void gemm256_8ph(
    const short* __restrict__ A, const short* __restrict__ BT,
    const float* __restrict__ bias, void* __restrict__ Cout,
    int N, int K)
{
    __shared__ short smem[2 * 2 * 2 * 16 * 512];   // 128 KiB

    const int t    = threadIdx.x;
    const int wave = t >> 6;
    const int lane = t & 63;
    const int quad = lane >> 4;
    const int lo   = lane & 15;
    const int wm   = wave >> 2;        // 0..1
    const int wn   = wave & 3;         // 0..3
    const int wm8  = wm * 8;
    const int wn4  = wn * 4;
    const int bn0  = blockIdx.x * 256;
    const int bm0  = blockIdx.y * 256;

    // Per-thread global sources for staging (fragment-order permutation is
    // applied here; LDS dest stays linear).  Line j covers subtile j*8+wave.
    const int rO = quad * 8;
    const short* gA0 = A  + (size_t)(bm0 + wave * 16 + lo) * K + rO;
    const short* gA1 = A  + (size_t)(bm0 + (8 + wave) * 16 + lo) * K + rO;
    const short* gB0 = BT + (size_t)(bn0 + wave * 16 + lo) * K + rO;
    const short* gB1 = BT + (size_t)(bn0 + (8 + wave) * 16 + lo) * K + rO;

    f32x4 acc[8][4];
#pragma unroll
    for (int i = 0; i < 8; ++i)
#pragma unroll
        for (int j = 0; j < 4; ++j)
            acc[i][j] = (f32x4){0.f, 0.f, 0.f, 0.f};

    const int NT = K >> 6;   // K-tiles of 64 (K=1536 -> 24, even)

    // Prologue: tile0 fully (8 loads), then tile1's {B-k0, A-k0, B-k1}
    // (6 loads, matching steady-state stream positions ph6/7/8).
    STG_A(0, 0, 0); STG_A(0, 1, 0); STG_B(0, 0, 0); STG_B(0, 1, 0);
    STG_B(1, 0, 1); STG_A(1, 0, 1); STG_B(1, 1, 1);
    asm volatile("s_waitcnt vmcnt(6)" ::: "memory");   // tile0 landed
    asm volatile("" ::: "memory");
    __builtin_amdgcn_s_barrier();
    asm volatile("" ::: "memory");

    short8 af[4], bf[4];
#pragma unroll 1
    for (int it = 0; it < (NT >> 1); ++it) {
        const int T  = it * 2;
        const int t2 = min(T + 2, NT - 1);
        const int t3 = min(T + 3, NT - 1);
        PH(0, 0, 0, true,  STG_A(1, 1, T + 1), 0);   // ph1
        PH(0, 0, 1, false, STG_B(0, 0, t2),    0);   // ph2
        PH(0, 1, 0, true,  STG_A(0, 0, t2),    0);   // ph3
        PH(0, 1, 1, false, STG_B(0, 1, t2),    1);   // ph4  vmcnt(6)
        PH(1, 0, 0, true,  STG_A(0, 1, t2),    0);   // ph5
        PH(1, 0, 1, false, STG_B(1, 0, t3),    0);   // ph6
        PH(1, 1, 0, true,  STG_A(1, 0, t3),    0);   // ph7
        PH(1, 1, 1, false, STG_B(1, 1, t3),    1);   // ph8  vmcnt(6)
    }
    asm volatile("s_waitcnt vmcnt(0)" ::: "memory");

    // Epilogue: C = acc + bias.  col = bn0+wn*64+ni*16+lo,
    // row = bm0+wm*128+r8*16+quad*4+r  (16x16x32 C/D layout).
#pragma unroll
    for (int ni = 0; ni < 4; ++ni) {
        int col  = bn0 + wn * 64 + ni * 16 + lo;
        float bv = bias[col];
#pragma unroll
        for (int r8 = 0; r8 < 8; ++r8)
#pragma unroll
            for (int r = 0; r < 4; ++r) {
                int row   = bm0 + wm * 128 + r8 * 16 + quad * 4 + r;
                float val = acc[r8][ni][r] + bv;
                if (OUT_BF16)
                    ((short*)Cout)[(size_t)row * N + col] = f2b(val);
                else
                    ((float*)Cout)[(size_t)row * N + col] = val;
            }
    }
}

// ---------------------------------------------------------------------------
// Flash attention full heads, split-K x4, fixed-m=0 softmax.  (unchanged)
// ---------------------------------------------------------------------------
#define KSP 136
#define VTP 44
#define PLP 40

__global__ __launch_bounds__(256) void attn_full_split(
    const short* __restrict__ qkv, short* __restrict__ Opart,
    float* __restrict__ lsum)
{
    const int pair = blockIdx.y;
    const int b    = pair / 6;
    const int h    = pair % 6;
    const int q0   = blockIdx.x * 64;
    const int kz   = blockIdx.z;
    const int t    = threadIdx.x;
    const int wave = t >> 6;
    const int lane = t & 63;
    const int quad = lane >> 4;
    const int lo   = lane & 15;

    __shared__ short Ks[32 * KSP];
    __shared__ short Vr[32 * KSP];
    __shared__ short Vt[128 * VTP];
    __shared__ short Pl[4][16 * PLP];

    const short* base = qkv + (size_t)b * SEQ * QKVROW;

    short8 qf[4];
    {
        int qrow = q0 + wave * 16 + lo;
        const short* qp = base + (size_t)qrow * QKVROW + h * HD;
        for (int c = 0; c < 4; ++c)
            qf[c] = *(const short8*)(qp + c * 32 + quad * 8);
    }

    f32x4 o[8];
    for (int i = 0; i < 8; ++i) o[i] = (f32x4){0.f, 0.f, 0.f, 0.f};
    float lrow[4] = {0.f, 0.f, 0.f, 0.f};

    const int skey = t >> 3;
    const int sdc  = (t & 7) * 16;
    const int thd  = t & 127;
    const int tkc  = (t >> 7) * 16;

    const int kend = kz * KRANGE + KRANGE;
    for (int k0 = kz * KRANGE; k0 < kend; k0 += 32) {
        {
            const short* kro = base + (size_t)(k0 + skey) * QKVROW + DMODEL     + h * HD + sdc;
            const short* vro = base + (size_t)(k0 + skey) * QKVROW + 2 * DMODEL + h * HD + sdc;
            short8 ka = *(const short8*)kro;
            short8 kb = *(const short8*)(kro + 8);
            short8 va = *(const short8*)vro;
            short8 vb = *(const short8*)(vro + 8);
            *(short8*)(Ks + skey * KSP + sdc)     = ka;
            *(short8*)(Ks + skey * KSP + sdc + 8) = kb;
            *(short8*)(Vr + skey * KSP + sdc)     = va;
            *(short8*)(Vr + skey * KSP + sdc + 8) = vb;
        }
        __syncthreads();

        {
            short8 x0, x1;
            for (int j = 0; j < 8; ++j) x0[j] = Vr[(tkc + j) * KSP + thd];
            for (int j = 0; j < 8; ++j) x1[j] = Vr[(tkc + 8 + j) * KSP + thd];
            *(short8*)(Vt + thd * VTP + tkc)     = x0;
            *(short8*)(Vt + thd * VTP + tkc + 8) = x1;
        }

        f32x4 s[2];
        s[0] = (f32x4){0.f, 0.f, 0.f, 0.f};
        s[1] = (f32x4){0.f, 0.f, 0.f, 0.f};
        for (int g = 0; g < 2; ++g)
            for (int c = 0; c < 4; ++c) {
                short8 kf = *(const short8*)(Ks + (g * 16 + lo) * KSP + c * 32 + quad * 8);
                s[g] = __builtin_amdgcn_mfma_f32_16x16x32_bf16(qf[c], kf, s[g], 0, 0, 0);
            }

        for (int g = 0; g < 2; ++g)
            for (int r = 0; r < 4; ++r) {
                float p = __expf(s[g][r] * SCALE);
                lrow[r] += p;
                Pl[wave][(quad * 4 + r) * PLP + g * 16 + lo] = f2b(p);
            }
        __syncthreads();

        short8 pf = *(const short8*)(&Pl[wave][lo * PLP + quad * 8]);
        for (int ni = 0; ni < 8; ++ni) {
            short8 vf = *(const short8*)(Vt + (ni * 16 + lo) * VTP + quad * 8);
            o[ni] = __builtin_amdgcn_mfma_f32_16x16x32_bf16(pf, vf, o[ni], 0, 0, 0);
        }
    }

    for (int r = 0; r < 4; ++r)
        for (int off = 1; off < 16; off <<= 1)
            lrow[r] += __shfl_xor(lrow[r], off, 64);

    for (int ni = 0; ni < 8; ++ni)
        for (int r = 0; r < 4; ++r) {
            int grow = pair * SEQ + q0 + wave * 16 + quad * 4 + r;
            Opart[(size_t)kz * OPART_ELEMS + (size_t)grow * HD + ni * 16 + lo] =
                f2b(o[ni][r]);
        }
    if (lo == 0)
        for (int r = 0; r < 4; ++r) {
            int grow = pair * SEQ + q0 + wave * 16 + quad * 4 + r;
            lsum[kz * ROWS_P + grow] = lrow[r];
        }
}

// ---------------------------------------------------------------------------
// Local heads (h=6..9), banded-flash MFMA.  (unchanged)
// ---------------------------------------------------------------------------
__global__ __launch_bounds__(256) void attn_local_mfma(
    const short* __restrict__ qkv, short* __restrict__ att)
{
    const int pair = blockIdx.y;          // 0..7
    const int b    = pair >> 2;
    const int h    = 6 + (pair & 3);
    const int q0   = blockIdx.x * 64;
    const int t    = threadIdx.x;
    const int wave = t >> 6;
    const int lane = t & 63;
    const int quad = lane >> 4;
    const int lo   = lane & 15;

    __shared__ short Ks[32 * KSP];
    __shared__ short Vr[32 * KSP];
    __shared__ short Vt[128 * VTP];
    __shared__ short Pl[4][16 * PLP];

    const short* base = qkv + (size_t)b * SEQ * QKVROW;

    short8 qf[4];
    {
        int qrow = q0 + wave * 16 + lo;
        const short* qp = base + (size_t)qrow * QKVROW + h * HD;
        for (int c = 0; c < 4; ++c)
            qf[c] = *(const short8*)(qp + c * 32 + quad * 8);
    }

    f32x4 o[8];
    for (int i = 0; i < 8; ++i) o[i] = (f32x4){0.f, 0.f, 0.f, 0.f};
    float lrow[4] = {0.f, 0.f, 0.f, 0.f};

    const int skey = t >> 3;
    const int sdc  = (t & 7) * 16;
    const int thd  = t & 127;
    const int tkc  = (t >> 7) * 16;
    const int irow = q0 + wave * 16 + quad * 4;   // query row = irow + r

    const int ks = max(0, q0 - 32);
    const int ke = min(SEQ, q0 + 96);
    for (int k0 = ks; k0 < ke; k0 += 32) {
        {
            const short* kro = base + (size_t)(k0 + skey) * QKVROW + DMODEL     + h * HD + sdc;
            const short* vro = base + (size_t)(k0 + skey) * QKVROW + 2 * DMODEL + h * HD + sdc;
            short8 ka = *(const short8*)kro;
            short8 kb = *(const short8*)(kro + 8);
            short8 va = *(const short8*)vro;
            short8 vb = *(const short8*)(vro + 8);
            *(short8*)(Ks + skey * KSP + sdc)     = ka;
            *(short8*)(Ks + skey * KSP + sdc + 8) = kb;
            *(short8*)(Vr + skey * KSP + sdc)     = va;
            *(short8*)(Vr + skey * KSP + sdc + 8) = vb;
        }
        __syncthreads();   // B1

        {
            short8 x0, x1;
            for (int j = 0; j < 8; ++j) x0[j] = Vr[(tkc + j) * KSP + thd];
            for (int j = 0; j < 8; ++j) x1[j] = Vr[(tkc + 8 + j) * KSP + thd];
            *(short8*)(Vt + thd * VTP + tkc)     = x0;
            *(short8*)(Vt + thd * VTP + tkc + 8) = x1;
        }

        f32x4 s[2];
        s[0] = (f32x4){0.f, 0.f, 0.f, 0.f};
        s[1] = (f32x4){0.f, 0.f, 0.f, 0.f};
        for (int g = 0; g < 2; ++g)
            for (int c = 0; c < 4; ++c) {
                short8 kf = *(const short8*)(Ks + (g * 16 + lo) * KSP + c * 32 + quad * 8);
                s[g] = __builtin_amdgcn_mfma_f32_16x16x32_bf16(qf[c], kf, s[g], 0, 0, 0);
            }

        // mask |i-j|<=32, p=exp(s*scale) else 0
        for (int g = 0; g < 2; ++g)
            for (int r = 0; r < 4; ++r) {
                int j = k0 + g * 16 + lo;
                int d = irow + r - j;
                float p = (d >= -32 && d <= 32) ? __expf(s[g][r] * SCALE) : 0.f;
                lrow[r] += p;
                Pl[wave][(quad * 4 + r) * PLP + g * 16 + lo] = f2b(p);
            }
        __syncthreads();   // B2

        short8 pf = *(const short8*)(&Pl[wave][lo * PLP + quad * 8]);
        for (int ni = 0; ni < 8; ++ni) {
            short8 vf = *(const short8*)(Vt + (ni * 16 + lo) * VTP + quad * 8);
            o[ni] = __builtin_amdgcn_mfma_f32_16x16x32_bf16(pf, vf, o[ni], 0, 0, 0);
        }
    }

    for (int r = 0; r < 4; ++r)
        for (int off = 1; off < 16; off <<= 1)
            lrow[r] += __shfl_xor(lrow[r], off, 64);

    for (int ni = 0; ni < 8; ++ni)
        for (int r = 0; r < 4; ++r) {
            int row = irow + r;
            size_t off = ((size_t)(b * SEQ + row)) * DMODEL + h * HD + ni * 16 + lo;
            att[off] = f2b(o[ni][r] / lrow[r]);
        }
}

// ---------------------------------------------------------------------------
// Fused post-attention: merge (heads 0-5) + global (10-11).  (unchanged)
// ---------------------------------------------------------------------------
#define MERGE_BLOCKS  12288   // NPAIR*SEQ*HD/256
#define GLOBAL_BLOCKS 2048    // (SEQ/4)*4

__global__ __launch_bounds__(256) void postattn_k(
    const short* __restrict__ qkv, const short* __restrict__ Opart,
    const float* __restrict__ lsum, short* __restrict__ att)
{
    const int bid  = blockIdx.x;
    const int t    = threadIdx.x;
    const int wave = t >> 6;
    const int lane = t & 63;

    if (bid < MERGE_BLOCKS) {
        int idx  = bid * 256 + t;
        int pair = idx >> 18;
        int q    = (idx >> 7) & (SEQ - 1);
        int hd   = idx & (HD - 1);
        int row  = pair * SEQ + q;
        float osum = 0.f, ls = 0.f;
        for (int z = 0; z < NSPLIT; ++z) {
            ls   += lsum[z * ROWS_P + row];
            osum += b2f(Opart[(size_t)z * OPART_ELEMS + (size_t)row * HD + hd]);
        }
        int b = pair / 6, h = pair % 6;
        att[((size_t)(b * SEQ + q)) * DMODEL + h * HD + hd] = f2b(osum / ls);
    } else {
        int gb   = bid - MERGE_BLOCKS;
        int pair = gb >> 9;               // 0..3
        int q    = (gb & 511) * 4 + wave;
        int b    = pair >> 1;
        int h    = 10 + (pair & 1);

        const short* base = qkv + (size_t)b * SEQ * QKVROW;
        const short* qp   = base + (size_t)q * QKVROW + h * HD;
        const short* k0   = base + DMODEL + h * HD;
        const short* k1   = base + (size_t)(SEQ - 1) * QKVROW + DMODEL + h * HD;

        float s0 = fmaf(b2f(qp[lane]), b2f(k0[lane]),
                   b2f(qp[lane + 64]) * b2f(k0[lane + 64]));
        float s1 = fmaf(b2f(qp[lane]), b2f(k1[lane]),
                   b2f(qp[lane + 64]) * b2f(k1[lane + 64]));
        for (int off = 1; off < 64; off <<= 1) {
            s0 += __shfl_xor(s0, off, 64);
            s1 += __shfl_xor(s1, off, 64);
        }
        s0 *= SCALE; s1 *= SCALE;
        float m  = fmaxf(s0, s1);
        float e0 = __expf(s0 - m), e1 = __expf(s1 - m);
        float inv = 1.f / (e0 + e1);
        float p0 = e0 * inv, p1 = e1 * inv;

        const short* v0 = base + 2 * DMODEL + h * HD;
        const short* v1 = base + (size_t)(SEQ - 1) * QKVROW + 2 * DMODEL + h * HD;
        size_t ob = ((size_t)(b * SEQ + q)) * DMODEL + h * HD;
        att[ob + lane]      = f2b(fmaf(p0, b2f(v0[lane]),      p1 * b2f(v1[lane])));
        att[ob + lane + 64] = f2b(fmaf(p0, b2f(v0[lane + 64]), p1 * b2f(v1[lane + 64])));
    }
}

// ---------------------------------------------------------------------------
extern "C" void kernel_launch(void* const* d_in, const int* in_sizes, int n_in,
                              void* d_out, int out_size, void* d_ws, size_t ws_size,
                              hipStream_t stream) {
    const float* x    = (const float*)d_in[0];
    const float* Wqkv = (const float*)d_in[1];
    const float* bqkv = (const float*)d_in[2];
    const float* Wout = (const float*)d_in[3];
    const float* bout = (const float*)d_in[4];

    // ws layout (~94.8 MB): att aliases xb (xb dead after GEMM1).
    char* p = (char*)d_ws;
    short* qkv   = (short*)p;  p += (size_t)TOK * QKVROW * 2;      // 37.75 MB
    short* Opart = (short*)p;  p += OPART_ELEMS * NSPLIT * 2;      // 25.17 MB
    float* lsum  = (float*)p;  p += (size_t)ROWS_P * NSPLIT * 4;   // 0.39 MB
    short* xb    = (short*)p;  p += (size_t)TOK * DMODEL * 2;      // 12.58 MB
    short* att   = xb;                                             // alias
    short* WqkvT = (short*)p;  p += (size_t)QKVROW * DMODEL * 2;   // 14.16 MB
    short* WoutT = (short*)p;                                      // 4.72 MB

    // 0) fused prepass
    prepass_k<<<dim3(CVT_BLOCKS + TQKV_BLOCKS + TOUT_BLOCKS), 256, 0, stream>>>(
        x, Wqkv, Wout, xb, WqkvT, WoutT);
    // 1) QKV = x @ Wqkv + bqkv   (bf16 out), 256^2 8-phase, grid 18x16
    gemm256_8ph<true><<<dim3(QKVROW / 256, TOK / 256), 512, 0, stream>>>(
        xb, WqkvT, bqkv, (void*)qkv, QKVROW, DMODEL);
    // 2) attention: full split-K + banded local MFMA + fused merge/global
    attn_full_split<<<dim3(SEQ / 64, NPAIR, NSPLIT), 256, 0, stream>>>(qkv, Opart, lsum);
    attn_local_mfma<<<dim3(SEQ / 64, 8), 256, 0, stream>>>(qkv, att);
    postattn_k<<<dim3(MERGE_BLOCKS + GLOBAL_BLOCKS), 256, 0, stream>>>(
        qkv, Opart, lsum, att);
    // 3) out = att @ Wout + bout  (fp32 out), 256^2 8-phase, grid 6x16
    gemm256_8ph<false><<<dim3(DMODEL / 256, TOK / 256), 512, 0, stream>>>(
        att, WoutT, bout, d_out, DMODEL, DMODEL);
}

// Round 2
// 336.821 us; speedup vs baseline: 1.0266x; 1.0266x over previous
//
#include <hip/hip_runtime.h>
#include <hip/hip_bf16.h>

// Problem constants (B=2, S=2048, DIM=1536, 12 heads x hd=128)
// Inputs fp32; OUTPUT fp32. Workspace ~94.8 MB (see kernel_launch).
#define SEQ    2048
#define TOK    4096          // B*S
#define DMODEL 1536
#define QKVROW 4608          // 3*DMODEL
#define HD     128
#define SCALE  0.08838834764831845f  // 1/sqrt(128)

#define NSPLIT 4
#define KRANGE (SEQ / NSPLIT)
#define NPAIR  12
#define ROWS_P (NPAIR * SEQ)
#define OPART_ELEMS ((size_t)ROWS_P * HD)

typedef __attribute__((ext_vector_type(8))) short short8;
typedef __attribute__((ext_vector_type(4))) short short4v;
typedef __attribute__((ext_vector_type(4))) float f32x4;

__device__ __forceinline__ float b2f(short s) {
    union { unsigned u; float f; } x;
    x.u = ((unsigned)(unsigned short)s) << 16;
    return x.f;
}
__device__ __forceinline__ short f2b(float f) {
    union { float f; unsigned u; } x; x.f = f;
    unsigned u = x.u;
    unsigned r = (u + 0x7fffu + ((u >> 16) & 1u)) >> 16;  // RNE
    return (short)r;
}

// async 16B global->LDS (m97 pattern). LDS dest: wave-uniform base + lane*16.
__device__ __forceinline__ void gld_lds16(const short* g, short* l) {
    __builtin_amdgcn_global_load_lds(
        (__attribute__((address_space(1))) void*)(g),
        (__attribute__((address_space(3))) void*)(l), 16, 0, 0);
}

// ---------------------------------------------------------------------------
// Fused prepass: x fp32->bf16, Wqkv/Wout fp32 -> transposed bf16.
// ---------------------------------------------------------------------------
#define CVT_BLOCKS  6144   // TOK*DMODEL / 1024
#define TQKV_BLOCKS 1728   // (QKVROW/64)*(DMODEL/64)
#define TOUT_BLOCKS 576    // (DMODEL/64)*(DMODEL/64)

__device__ __forceinline__ void transpose_tile(
    const float* __restrict__ W, short* __restrict__ WT,
    int K, int N, int k0, int n0, int t, short (*tile)[65])
{
    {
        int j  = t & 63;
        int i0 = (t >> 6) * 16;
        for (int ii = 0; ii < 16; ++ii)
            tile[i0 + ii][j] = f2b(W[(size_t)(k0 + i0 + ii) * N + n0 + j]);
    }
    __syncthreads();
    {
        int i  = t & 63;
        int j0 = (t >> 6) * 16;
        for (int jj = 0; jj < 16; ++jj)
            WT[(size_t)(n0 + j0 + jj) * K + k0 + i] = tile[i][j0 + jj];
    }
}

__global__ __launch_bounds__(256) void prepass_k(
    const float* __restrict__ x, const float* __restrict__ Wqkv,
    const float* __restrict__ Wout, short* __restrict__ xb,
    short* __restrict__ WqkvT, short* __restrict__ WoutT)
{
    __shared__ short tile[64][65];
    const int bid = blockIdx.x;
    const int t   = threadIdx.x;
    if (bid < CVT_BLOCKS) {
        int i = bid * 1024 + t * 4;
        float4 v = *(const float4*)(x + i);
        short4v b = { f2b(v.x), f2b(v.y), f2b(v.z), f2b(v.w) };
        *(short4v*)(xb + i) = b;
    } else if (bid < CVT_BLOCKS + TQKV_BLOCKS) {
        int tb = bid - CVT_BLOCKS;
        transpose_tile(Wqkv, WqkvT, DMODEL, QKVROW,
                       (tb / (QKVROW / 64)) * 64, (tb % (QKVROW / 64)) * 64, t, tile);
    } else {
        int tb = bid - (CVT_BLOCKS + TQKV_BLOCKS);
        transpose_tile(Wout, WoutT, DMODEL, DMODEL,
                       (tb / (DMODEL / 64)) * 64, (tb % (DMODEL / 64)) * 64, t, tile);
    }
}

// ---------------------------------------------------------------------------
// GEMM: 128x256 tile, BK=64, 8-phase counted-vmcnt schedule (T3+T4+T5),
// XCD-chunked supertile grid mapping (T1, m204 bijective).
//   C[M,N] = A[M,K] @ BT[N,K]^T + bias[N].
// 512 threads = 8 waves (2M x 4N); per-wave output 64x64; acc[4][4] f32x4.
// LDS 96 KiB, FRAGMENT-ORDER subtiles [lane][16B]: every ds_read_b128 is
// base + lane*16 -> conflict-free; global_load_lds (wave-uniform LDS dest)
// gets the permutation on the GLOBAL address side (m173 pattern).
//
// Stage unit = one matrix's K-half: A = 128x32 = 8 KB = 1 gld_lds16/thread;
// B = 256x32 = 16 KB = 2 gld_lds16/thread.  Steady-state per iteration
// (2 K-tiles, tiles T in slot0 ph1-4, T+1 in slot1 ph5-8):
//   ph1: A-k1(T+1)->s1 [1]  ph2: B-k0(T+2)->s0 [2]  ph3: A-k0(T+2)->s0 [1]
//   ph4: B-k1(T+2)->s0 [2] + vmcnt(5)               ph5: A-k1(T+2)->s0 [1]
//   ph6: B-k0(T+3)->s1 [2]  ph7: A-k0(T+3)->s1 [1]  ph8: B-k1(T+3)->s1 [2]
//        + vmcnt(5)
// vmcnt(5) = loads of the 3 most recent units (2+1+2); at each boundary the
// upcoming tile's units are exactly the issues older than the newest 3.
// Tail: kt clamped to NTK-1 (redundant re-stage of retired units, benign).
// ---------------------------------------------------------------------------
__device__ __forceinline__ short* ldsA(short* s, int slot, int kh, int st) {
    return s + ((slot * 2 + kh) * 8 + st) * 512;            // st in [0,8)
}
__device__ __forceinline__ short* ldsB(short* s, int slot, int kh, int st) {
    return s + 16384 + ((slot * 2 + kh) * 16 + st) * 512;   // st in [0,16)
}

template <int SLOT, int KH, int G>
__device__ __forceinline__ void ld_a(short8 af[2], short* smem, int wm4, int lane) {
#pragma unroll
    for (int mi = 0; mi < 2; ++mi)
        af[mi] = *(const short8*)(ldsA(smem, SLOT, KH, wm4 + G * 2 + mi) + lane * 8);
}
template <int SLOT, int KH>
__device__ __forceinline__ void ld_b(short8 bf[4], short* smem, int wn4, int lane) {
#pragma unroll
    for (int ni = 0; ni < 4; ++ni)
        bf[ni] = *(const short8*)(ldsB(smem, SLOT, KH, wn4 + ni) + lane * 8);
}
template <int G>
__device__ __forceinline__ void mfma8(f32x4 (&acc)[4][4], const short8 af[2], const short8 bf[4]) {
#pragma unroll
    for (int mi = 0; mi < 2; ++mi)
#pragma unroll
        for (int ni = 0; ni < 4; ++ni)
            acc[G * 2 + mi][ni] = __builtin_amdgcn_mfma_f32_16x16x32_bf16(
                af[mi], bf[ni], acc[G * 2 + mi][ni], 0, 0, 0);
}

#define STG_A(S, KH, KT) gld_lds16(gA0 + (KT) * 64 + (KH) * 32, ldsA(smem, (S), (KH), wave))
#define STG_B(S, KH, KT)                                                        \
    do {                                                                        \
        gld_lds16(gB0 + (KT) * 64 + (KH) * 32, ldsB(smem, (S), (KH), wave));    \
        gld_lds16(gB1 + (KT) * 64 + (KH) * 32, ldsB(smem, (S), (KH), 8 + wave));\
    } while (0)

#define PH(S, KH, G, LOADB, STG_STMT, VMW)                          \
    do {                                                            \
        ld_a<S, KH, G>(af, smem, wm4, lane);                        \
        if (LOADB) ld_b<S, KH>(bf, smem, wn4, lane);                \
        STG_STMT;                                                   \
        asm volatile("" ::: "memory");                              \
        __builtin_amdgcn_s_barrier();                               \
        asm volatile("s_waitcnt lgkmcnt(0)" ::: "memory");          \
        __builtin_amdgcn_s_setprio(1);                              \
        mfma8<G>(acc, af, bf);                                      \
        __builtin_amdgcn_s_setprio(0);                              \
        if (VMW) asm volatile("s_waitcnt vmcnt(5)" ::: "memory");   \
        asm volatile("" ::: "memory");                              \
        __builtin_amdgcn_s_barrier();                               \
        asm volatile("" ::: "memory");                              \
    } while (0)

template <bool OUT_BF16, int MT, int NT>
__global__ __launch_bounds__(512, 2) void gemm128x256_8ph(
    const short* __restrict__ A, const short* __restrict__ BT,
    const float* __restrict__ bias, void* __restrict__ Cout,
    int N, int K)
{
    __shared__ short smem[49152];   // 96 KiB: A 32 KB + B 64 KB

    // --- XCD-chunked bijective grid map (m204) + 4-wide N-band supertile ---
    // Consecutive wg within an XCD chunk sweep (mt-major, 4 N-cols fastest):
    // 32 co-resident blocks ~ 8 A-panels + 4 B-panels ~ 6 MB -> L2-friendly.
    constexpr int NWG = MT * NT;
    constexpr int Q8  = NWG / 8, R8 = NWG % 8;
    constexpr int BW  = 4;
    constexpr int FULLB = NT / BW;
    constexpr int TB  = FULLB * MT * BW;
    constexpr int TW  = NT - FULLB * BW;
    const int orig = blockIdx.x;
    const int xcd  = orig & 7, idx = orig >> 3;
    const int wg   = (xcd < R8 ? xcd * (Q8 + 1) : R8 * (Q8 + 1) + (xcd - R8) * Q8) + idx;
    int mt, nt;
    if (TW == 0 || wg < TB) {
        int band = wg / (MT * BW);
        int rem  = wg % (MT * BW);
        mt = rem / BW;
        nt = band * BW + rem % BW;
    } else {
        constexpr int TWD = TW ? TW : 1;
        int rem = wg - TB;
        mt = rem / TWD;
        nt = FULLB * BW + rem % TWD;
    }
    const int bm0 = mt * 128;
    const int bn0 = nt * 256;

    const int t    = threadIdx.x;
    const int wave = t >> 6;
    const int lane = t & 63;
    const int quad = lane >> 4;
    const int lo   = lane & 15;
    const int wm   = wave >> 2;        // 0..1  (M)
    const int wn   = wave & 3;         // 0..3  (N)
    const int wm4  = wm * 4;
    const int wn4  = wn * 4;

    // Per-thread global sources for staging (fragment-order permutation on
    // the GLOBAL side; LDS dest stays linear).
    const int rO = quad * 8;
    const short* gA0 = A  + (size_t)(bm0 + wave * 16 + lo) * K + rO;
    const short* gB0 = BT + (size_t)(bn0 + wave * 16 + lo) * K + rO;
    const short* gB1 = BT + (size_t)(bn0 + (8 + wave) * 16 + lo) * K + rO;

    f32x4 acc[4][4];
#pragma unroll
    for (int i = 0; i < 4; ++i)
#pragma unroll
        for (int j = 0; j < 4; ++j)
            acc[i][j] = (f32x4){0.f, 0.f, 0.f, 0.f};

    const int NTK = K >> 6;   // K-tiles of 64 (K=1536 -> 24, even)

    // Prologue: tile0 fully (6 loads), then tile1's {B-k0, A-k0, B-k1}
    // (5 loads, matching steady-state stream positions ph6/7/8).
    STG_A(0, 0, 0); STG_A(0, 1, 0); STG_B(0, 0, 0); STG_B(0, 1, 0);
    STG_B(1, 0, 1); STG_A(1, 0, 1); STG_B(1, 1, 1);
    asm volatile("s_waitcnt vmcnt(5)" ::: "memory");   // tile0 landed
    asm volatile("" ::: "memory");
    __builtin_amdgcn_s_barrier();
    asm volatile("" ::: "memory");

    short8 af[2], bf[4];
#pragma unroll 1
    for (int it = 0; it < (NTK >> 1); ++it) {
        const int T  = it * 2;
        const int t2 = min(T + 2, NTK - 1);
        const int t3 = min(T + 3, NTK - 1);
        PH(0, 0, 0, true,  STG_A(1, 1, T + 1), 0);   // ph1
        PH(0, 0, 1, false, STG_B(0, 0, t2),    0);   // ph2
        PH(0, 1, 0, true,  STG_A(0, 0, t2),    0);   // ph3
        PH(0, 1, 1, false, STG_B(0, 1, t2),    1);   // ph4  vmcnt(5)
        PH(1, 0, 0, true,  STG_A(0, 1, t2),    0);   // ph5
        PH(1, 0, 1, false, STG_B(1, 0, t3),    0);   // ph6
        PH(1, 1, 0, true,  STG_A(1, 0, t3),    0);   // ph7
        PH(1, 1, 1, false, STG_B(1, 1, t3),    1);   // ph8  vmcnt(5)
    }
    asm volatile("s_waitcnt vmcnt(0)" ::: "memory");

    // Epilogue: C = acc + bias.  col = bn0+wn*64+ni*16+lo,
    // row = bm0+wm*64+mi*16+quad*4+r  (16x16x32 C/D layout).
#pragma unroll
    for (int ni = 0; ni < 4; ++ni) {
        int col  = bn0 + wn * 64 + ni * 16 + lo;
        float bv = bias[col];
#pragma unroll
        for (int mi = 0; mi < 4; ++mi)
#pragma unroll
            for (int r = 0; r < 4; ++r) {
                int row   = bm0 + wm * 64 + mi * 16 + quad * 4 + r;
                float val = acc[mi][ni][r] + bv;
                if (OUT_BF16)
                    ((short*)Cout)[(size_t)row * N + col] = f2b(val);
                else
                    ((float*)Cout)[(size_t)row * N + col] = val;
            }
    }
}

// ---------------------------------------------------------------------------
// Flash attention full heads, split-K x4, fixed-m=0 softmax.  (unchanged)
// ---------------------------------------------------------------------------
#define KSP 136
#define VTP 44
#define PLP 40

__global__ __launch_bounds__(256) void attn_full_split(
    const short* __restrict__ qkv, short* __restrict__ Opart,
    float* __restrict__ lsum)
{
    const int pair = blockIdx.y;
    const int b    = pair / 6;
    const int h    = pair % 6;
    const int q0   = blockIdx.x * 64;
    const int kz   = blockIdx.z;
    const int t    = threadIdx.x;
    const int wave = t >> 6;
    const int lane = t & 63;
    const int quad = lane >> 4;
    const int lo   = lane & 15;

    __shared__ short Ks[32 * KSP];
    __shared__ short Vr[32 * KSP];
    __shared__ short Vt[128 * VTP];
    __shared__ short Pl[4][16 * PLP];

    const short* base = qkv + (size_t)b * SEQ * QKVROW;

    short8 qf[4];
    {
        int qrow = q0 + wave * 16 + lo;
        const short* qp = base + (size_t)qrow * QKVROW + h * HD;
        for (int c = 0; c < 4; ++c)
            qf[c] = *(const short8*)(qp + c * 32 + quad * 8);
    }

    f32x4 o[8];
    for (int i = 0; i < 8; ++i) o[i] = (f32x4){0.f, 0.f, 0.f, 0.f};
    float lrow[4] = {0.f, 0.f, 0.f, 0.f};

    const int skey = t >> 3;
    const int sdc  = (t & 7) * 16;
    const int thd  = t & 127;
    const int tkc  = (t >> 7) * 16;

    const int kend = kz * KRANGE + KRANGE;
    for (int k0 = kz * KRANGE; k0 < kend; k0 += 32) {
        {
            const short* kro = base + (size_t)(k0 + skey) * QKVROW + DMODEL     + h * HD + sdc;
            const short* vro = base + (size_t)(k0 + skey) * QKVROW + 2 * DMODEL + h * HD + sdc;
            short8 ka = *(const short8*)kro;
            short8 kb = *(const short8*)(kro + 8);
            short8 va = *(const short8*)vro;
            short8 vb = *(const short8*)(vro + 8);
            *(short8*)(Ks + skey * KSP + sdc)     = ka;
            *(short8*)(Ks + skey * KSP + sdc + 8) = kb;
            *(short8*)(Vr + skey * KSP + sdc)     = va;
            *(short8*)(Vr + skey * KSP + sdc + 8) = vb;
        }
        __syncthreads();

        {
            short8 x0, x1;
            for (int j = 0; j < 8; ++j) x0[j] = Vr[(tkc + j) * KSP + thd];
            for (int j = 0; j < 8; ++j) x1[j] = Vr[(tkc + 8 + j) * KSP + thd];
            *(short8*)(Vt + thd * VTP + tkc)     = x0;
            *(short8*)(Vt + thd * VTP + tkc + 8) = x1;
        }

        f32x4 s[2];
        s[0] = (f32x4){0.f, 0.f, 0.f, 0.f};
        s[1] = (f32x4){0.f, 0.f, 0.f, 0.f};
        for (int g = 0; g < 2; ++g)
            for (int c = 0; c < 4; ++c) {
                short8 kf = *(const short8*)(Ks + (g * 16 + lo) * KSP + c * 32 + quad * 8);
                s[g] = __builtin_amdgcn_mfma_f32_16x16x32_bf16(qf[c], kf, s[g], 0, 0, 0);
            }

        for (int g = 0; g < 2; ++g)
            for (int r = 0; r < 4; ++r) {
                float p = __expf(s[g][r] * SCALE);
                lrow[r] += p;
                Pl[wave][(quad * 4 + r) * PLP + g * 16 + lo] = f2b(p);
            }
        __syncthreads();

        short8 pf = *(const short8*)(&Pl[wave][lo * PLP + quad * 8]);
        for (int ni = 0; ni < 8; ++ni) {
            short8 vf = *(const short8*)(Vt + (ni * 16 + lo) * VTP + quad * 8);
            o[ni] = __builtin_amdgcn_mfma_f32_16x16x32_bf16(pf, vf, o[ni], 0, 0, 0);
        }
    }

    for (int r = 0; r < 4; ++r)
        for (int off = 1; off < 16; off <<= 1)
            lrow[r] += __shfl_xor(lrow[r], off, 64);

    for (int ni = 0; ni < 8; ++ni)
        for (int r = 0; r < 4; ++r) {
            int grow = pair * SEQ + q0 + wave * 16 + quad * 4 + r;
            Opart[(size_t)kz * OPART_ELEMS + (size_t)grow * HD + ni * 16 + lo] =
                f2b(o[ni][r]);
        }
    if (lo == 0)
        for (int r = 0; r < 4; ++r) {
            int grow = pair * SEQ + q0 + wave * 16 + quad * 4 + r;
            lsum[kz * ROWS_P + grow] = lrow[r];
        }
}

// ---------------------------------------------------------------------------
// Local heads (h=6..9), banded-flash MFMA.  (unchanged)
// ---------------------------------------------------------------------------
__global__ __launch_bounds__(256) void attn_local_mfma(
    const short* __restrict__ qkv, short* __restrict__ att)
{
    const int pair = blockIdx.y;          // 0..7
    const int b    = pair >> 2;
    const int h    = 6 + (pair & 3);
    const int q0   = blockIdx.x * 64;
    const int t    = threadIdx.x;
    const int wave = t >> 6;
    const int lane = t & 63;
    const int quad = lane >> 4;
    const int lo   = lane & 15;

    __shared__ short Ks[32 * KSP];
    __shared__ short Vr[32 * KSP];
    __shared__ short Vt[128 * VTP];
    __shared__ short Pl[4][16 * PLP];

    const short* base = qkv + (size_t)b * SEQ * QKVROW;

    short8 qf[4];
    {
        int qrow = q0 + wave * 16 + lo;
        const short* qp = base + (size_t)qrow * QKVROW + h * HD;
        for (int c = 0; c < 4; ++c)
            qf[c] = *(const short8*)(qp + c * 32 + quad * 8);
    }

    f32x4 o[8];
    for (int i = 0; i < 8; ++i) o[i] = (f32x4){0.f, 0.f, 0.f, 0.f};
    float lrow[4] = {0.f, 0.f, 0.f, 0.f};

    const int skey = t >> 3;
    const int sdc  = (t & 7) * 16;
    const int thd  = t & 127;
    const int tkc  = (t >> 7) * 16;
    const int irow = q0 + wave * 16 + quad * 4;   // query row = irow + r

    const int ks = max(0, q0 - 32);
    const int ke = min(SEQ, q0 + 96);
    for (int k0 = ks; k0 < ke; k0 += 32) {
        {
            const short* kro = base + (size_t)(k0 + skey) * QKVROW + DMODEL     + h * HD + sdc;
            const short* vro = base + (size_t)(k0 + skey) * QKVROW + 2 * DMODEL + h * HD + sdc;
            short8 ka = *(const short8*)kro;
            short8 kb = *(const short8*)(kro + 8);
            short8 va = *(const short8*)vro;
            short8 vb = *(const short8*)(vro + 8);
            *(short8*)(Ks + skey * KSP + sdc)     = ka;
            *(short8*)(Ks + skey * KSP + sdc + 8) = kb;
            *(short8*)(Vr + skey * KSP + sdc)     = va;
            *(short8*)(Vr + skey * KSP + sdc + 8) = vb;
        }
        __syncthreads();   // B1

        {
            short8 x0, x1;
            for (int j = 0; j < 8; ++j) x0[j] = Vr[(tkc + j) * KSP + thd];
            for (int j = 0; j < 8; ++j) x1[j] = Vr[(tkc + 8 + j) * KSP + thd];
            *(short8*)(Vt + thd * VTP + tkc)     = x0;
            *(short8*)(Vt + thd * VTP + tkc + 8) = x1;
        }

        f32x4 s[2];
        s[0] = (f32x4){0.f, 0.f, 0.f, 0.f};
        s[1] = (f32x4){0.f, 0.f, 0.f, 0.f};
        for (int g = 0; g < 2; ++g)
            for (int c = 0; c < 4; ++c) {
                short8 kf = *(const short8*)(Ks + (g * 16 + lo) * KSP + c * 32 + quad * 8);
                s[g] = __builtin_amdgcn_mfma_f32_16x16x32_bf16(qf[c], kf, s[g], 0, 0, 0);
            }

        // mask |i-j|<=32, p=exp(s*scale) else 0
        for (int g = 0; g < 2; ++g)
            for (int r = 0; r < 4; ++r) {
                int j = k0 + g * 16 + lo;
                int d = irow + r - j;
                float p = (d >= -32 && d <= 32) ? __expf(s[g][r] * SCALE) : 0.f;
                lrow[r] += p;
                Pl[wave][(quad * 4 + r) * PLP + g * 16 + lo] = f2b(p);
            }
        __syncthreads();   // B2

        short8 pf = *(const short8*)(&Pl[wave][lo * PLP + quad * 8]);
        for (int ni = 0; ni < 8; ++ni) {
            short8 vf = *(const short8*)(Vt + (ni * 16 + lo) * VTP + quad * 8);
            o[ni] = __builtin_amdgcn_mfma_f32_16x16x32_bf16(pf, vf, o[ni], 0, 0, 0);
        }
    }

    for (int r = 0; r < 4; ++r)
        for (int off = 1; off < 16; off <<= 1)
            lrow[r] += __shfl_xor(lrow[r], off, 64);

    for (int ni = 0; ni < 8; ++ni)
        for (int r = 0; r < 4; ++r) {
            int row = irow + r;
            size_t off = ((size_t)(b * SEQ + row)) * DMODEL + h * HD + ni * 16 + lo;
            att[off] = f2b(o[ni][r] / lrow[r]);
        }
}

// ---------------------------------------------------------------------------
// Fused post-attention: merge (heads 0-5) + global (10-11).  (unchanged)
// ---------------------------------------------------------------------------
#define MERGE_BLOCKS  12288   // NPAIR*SEQ*HD/256
#define GLOBAL_BLOCKS 2048    // (SEQ/4)*4

__global__ __launch_bounds__(256) void postattn_k(
    const short* __restrict__ qkv, const short* __restrict__ Opart,
    const float* __restrict__ lsum, short* __restrict__ att)
{
    const int bid  = blockIdx.x;
    const int t    = threadIdx.x;
    const int wave = t >> 6;
    const int lane = t & 63;

    if (bid < MERGE_BLOCKS) {
        int idx  = bid * 256 + t;
        int pair = idx >> 18;
        int q    = (idx >> 7) & (SEQ - 1);
        int hd   = idx & (HD - 1);
        int row  = pair * SEQ + q;
        float osum = 0.f, ls = 0.f;
        for (int z = 0; z < NSPLIT; ++z) {
            ls   += lsum[z * ROWS_P + row];
            osum += b2f(Opart[(size_t)z * OPART_ELEMS + (size_t)row * HD + hd]);
        }
        int b = pair / 6, h = pair % 6;
        att[((size_t)(b * SEQ + q)) * DMODEL + h * HD + hd] = f2b(osum / ls);
    } else {
        int gb   = bid - MERGE_BLOCKS;
        int pair = gb >> 9;               // 0..3
        int q    = (gb & 511) * 4 + wave;
        int b    = pair >> 1;
        int h    = 10 + (pair & 1);

        const short* base = qkv + (size_t)b * SEQ * QKVROW;
        const short* qp   = base + (size_t)q * QKVROW + h * HD;
        const short* k0   = base + DMODEL + h * HD;
        const short* k1   = base + (size_t)(SEQ - 1) * QKVROW + DMODEL + h * HD;

        float s0 = fmaf(b2f(qp[lane]), b2f(k0[lane]),
                   b2f(qp[lane + 64]) * b2f(k0[lane + 64]));
        float s1 = fmaf(b2f(qp[lane]), b2f(k1[lane]),
                   b2f(qp[lane + 64]) * b2f(k1[lane + 64]));
        for (int off = 1; off < 64; off <<= 1) {
            s0 += __shfl_xor(s0, off, 64);
            s1 += __shfl_xor(s1, off, 64);
        }
        s0 *= SCALE; s1 *= SCALE;
        float m  = fmaxf(s0, s1);
        float e0 = __expf(s0 - m), e1 = __expf(s1 - m);
        float inv = 1.f / (e0 + e1);
        float p0 = e0 * inv, p1 = e1 * inv;

        const short* v0 = base + 2 * DMODEL + h * HD;
        const short* v1 = base + (size_t)(SEQ - 1) * QKVROW + 2 * DMODEL + h * HD;
        size_t ob = ((size_t)(b * SEQ + q)) * DMODEL + h * HD;
        att[ob + lane]      = f2b(fmaf(p0, b2f(v0[lane]),      p1 * b2f(v1[lane])));
        att[ob + lane + 64] = f2b(fmaf(p0, b2f(v0[lane + 64]), p1 * b2f(v1[lane + 64])));
    }
}

// ---------------------------------------------------------------------------
extern "C" void kernel_launch(void* const* d_in, const int* in_sizes, int n_in,
                              void* d_out, int out_size, void* d_ws, size_t ws_size,
                              hipStream_t stream) {
    const float* x    = (const float*)d_in[0];
    const float* Wqkv = (const float*)d_in[1];
    const float* bqkv = (const float*)d_in[2];
    const float* Wout = (const float*)d_in[3];
    const float* bout = (const float*)d_in[4];

    // ws layout (~94.8 MB): att aliases xb (xb dead after GEMM1).
    char* p = (char*)d_ws;
    short* qkv   = (short*)p;  p += (size_t)TOK * QKVROW * 2;      // 37.75 MB
    short* Opart = (short*)p;  p += OPART_ELEMS * NSPLIT * 2;      // 25.17 MB
    float* lsum  = (float*)p;  p += (size_t)ROWS_P * NSPLIT * 4;   // 0.39 MB
    short* xb    = (short*)p;  p += (size_t)TOK * DMODEL * 2;      // 12.58 MB
    short* att   = xb;                                             // alias
    short* WqkvT = (short*)p;  p += (size_t)QKVROW * DMODEL * 2;   // 14.16 MB
    short* WoutT = (short*)p;                                      // 4.72 MB

    // 0) fused prepass
    prepass_k<<<dim3(CVT_BLOCKS + TQKV_BLOCKS + TOUT_BLOCKS), 256, 0, stream>>>(
        x, Wqkv, Wout, xb, WqkvT, WoutT);
    // 1) QKV = x @ Wqkv + bqkv (bf16 out): 128x256 8-phase, 576 blocks
    gemm128x256_8ph<true, 32, 18><<<dim3(32 * 18), 512, 0, stream>>>(
        xb, WqkvT, bqkv, (void*)qkv, QKVROW, DMODEL);
    // 2) attention: full split-K + banded local MFMA + fused merge/global
    attn_full_split<<<dim3(SEQ / 64, NPAIR, NSPLIT), 256, 0, stream>>>(qkv, Opart, lsum);
    attn_local_mfma<<<dim3(SEQ / 64, 8), 256, 0, stream>>>(qkv, att);
    postattn_k<<<dim3(MERGE_BLOCKS + GLOBAL_BLOCKS), 256, 0, stream>>>(
        qkv, Opart, lsum, att);
    // 3) out = att @ Wout + bout (fp32 out): 128x256 8-phase, 192 blocks
    gemm128x256_8ph<false, 32, 6><<<dim3(32 * 6), 512, 0, stream>>>(
        att, WoutT, bout, d_out, DMODEL, DMODEL);
}